// Round 1
// baseline (50.616 us; speedup 1.0000x reference)
//
#include <hip/hip_runtime.h>

#define CUTN 128
#define CUT_SIZE 224
#define IMG_H 1024
#define IMG_W 1024
#define PAD 256          // IMG_H / 4
#define SIDE 1536        // IMG_H + 2*PAD

__global__ __launch_bounds__(256) void make_cutouts_kernel(
    const float* __restrict__ img,      // (3, 1024, 1024)
    const int* __restrict__ sizes_y,
    const int* __restrict__ sizes_x,
    const int* __restrict__ offs_y,
    const int* __restrict__ offs_x,
    float* __restrict__ out)            // (128, 3, 224, 224)
{
    const int perCut = CUT_SIZE * CUT_SIZE;
    int idx = blockIdx.x * blockDim.x + threadIdx.x;
    if (idx >= CUTN * perCut) return;

    int ch  = idx / perCut;
    int rem = idx - ch * perCut;
    int y   = rem / CUT_SIZE;
    int x   = rem - y * CUT_SIZE;

    float syf = (float)sizes_y[ch];
    float sxf = (float)sizes_x[ch];
    float oyf = (float)offs_y[ch];
    float oxf = (float)offs_x[ch];

    float gy = ((float)y + 0.5f) / (float)CUT_SIZE;
    float gx = ((float)x + 0.5f) / (float)CUT_SIZE;

    float ys = fminf(fmaxf(oyf + gy * syf - 0.5f, 0.0f), (float)(SIDE - 1));
    float xs = fminf(fmaxf(oxf + gx * sxf - 0.5f, 0.0f), (float)(SIDE - 1));

    int y0 = (int)floorf(ys);
    int x0 = (int)floorf(xs);
    int y1 = min(y0 + 1, SIDE - 1);
    int x1 = min(x0 + 1, SIDE - 1);
    float wy = ys - (float)y0;
    float wx = xs - (float)x0;

    // shift from padded coords to original-image coords; predicate zero pad
    int yy0 = y0 - PAD, yy1 = y1 - PAD;
    int xx0 = x0 - PAD, xx1 = x1 - PAD;
    bool vy0 = (unsigned)yy0 < (unsigned)IMG_H;
    bool vy1 = (unsigned)yy1 < (unsigned)IMG_H;
    bool vx0 = (unsigned)xx0 < (unsigned)IMG_W;
    bool vx1 = (unsigned)xx1 < (unsigned)IMG_W;

    float w00 = (1.0f - wy) * (1.0f - wx);
    float w01 = (1.0f - wy) * wx;
    float w10 = wy * (1.0f - wx);
    float w11 = wy * wx;

    long r0 = (long)yy0 * IMG_W;
    long r1 = (long)yy1 * IMG_W;

    #pragma unroll
    for (int c = 0; c < 3; ++c) {
        const float* plane = img + (size_t)c * IMG_H * IMG_W;
        float p00 = (vy0 && vx0) ? plane[r0 + xx0] : 0.0f;
        float p01 = (vy0 && vx1) ? plane[r0 + xx1] : 0.0f;
        float p10 = (vy1 && vx0) ? plane[r1 + xx0] : 0.0f;
        float p11 = (vy1 && vx1) ? plane[r1 + xx1] : 0.0f;
        float v = p00 * w00 + p01 * w01 + p10 * w10 + p11 * w11;
        out[(((size_t)ch * 3 + c) * CUT_SIZE + y) * CUT_SIZE + x] = v;
    }
}

extern "C" void kernel_launch(void* const* d_in, const int* in_sizes, int n_in,
                              void* d_out, int out_size, void* d_ws, size_t ws_size,
                              hipStream_t stream) {
    const float* img     = (const float*)d_in[0];
    const int*   sizes_y = (const int*)d_in[1];
    const int*   sizes_x = (const int*)d_in[2];
    const int*   offs_y  = (const int*)d_in[3];
    const int*   offs_x  = (const int*)d_in[4];
    // d_in[5] is cut_size scalar (==224), hardcoded.
    float* out = (float*)d_out;

    const int total = CUTN * CUT_SIZE * CUT_SIZE;   // 6,422,528 threads
    const int block = 256;
    const int grid  = (total + block - 1) / block;
    make_cutouts_kernel<<<grid, block, 0, stream>>>(img, sizes_y, sizes_x,
                                                    offs_y, offs_x, out);
}

// Round 2
// 46.055 us; speedup vs baseline: 1.0991x; 1.0991x over previous
//
#include <hip/hip_runtime.h>

#define CUTN 128
#define CUT_SIZE 224
#define IMG_H 1024
#define IMG_W 1024
#define PAD 256          // IMG_H / 4
#define SIDE 1536        // IMG_H + 2*PAD
#define BLOCKS_PER_CUT 196   // (224*224)/256 exactly -> cut index uniform per block

__global__ __launch_bounds__(256) void make_cutouts_kernel(
    const float* __restrict__ img,      // (3, 1024, 1024)
    const int* __restrict__ sizes_y,
    const int* __restrict__ sizes_x,
    const int* __restrict__ offs_y,
    const int* __restrict__ offs_x,
    float* __restrict__ out)            // (128, 3, 224, 224)
{
    const int bid = blockIdx.x;
    const int cut = bid / BLOCKS_PER_CUT;            // uniform per block
    const int rem = (bid - cut * BLOCKS_PER_CUT) * 256 + threadIdx.x;
    const int y   = rem / CUT_SIZE;
    const int x   = rem - y * CUT_SIZE;

    const float syf = (float)sizes_y[cut];
    const float sxf = (float)sizes_x[cut];
    const float oyf = (float)offs_y[cut];
    const float oxf = (float)offs_x[cut];

    const float gy = ((float)y + 0.5f) / (float)CUT_SIZE;
    const float gx = ((float)x + 0.5f) / (float)CUT_SIZE;

    const float ys = fminf(fmaxf(oyf + gy * syf - 0.5f, 0.0f), (float)(SIDE - 1));
    const float xs = fminf(fmaxf(oxf + gx * sxf - 0.5f, 0.0f), (float)(SIDE - 1));

    const int y0 = (int)floorf(ys);
    const int x0 = (int)floorf(xs);
    const float wy = ys - (float)y0;
    const float wx = xs - (float)x0;

    // padded -> original image coords; x1/y1 clamp at SIDE-1 is equivalent to
    // +1 then predicate (clamp only binds deep inside the right/bottom pad,
    // where both are out of image anyway).
    const int yy0 = y0 - PAD, yy1 = yy0 + 1;
    const int xx0 = x0 - PAD, xx1 = xx0 + 1;
    const bool vy0 = (unsigned)yy0 < (unsigned)IMG_H;
    const bool vy1 = (unsigned)yy1 < (unsigned)IMG_H;
    const bool vx0 = (unsigned)xx0 < (unsigned)IMG_W;
    const bool vx1 = (unsigned)xx1 < (unsigned)IMG_W;
    const bool vpair = vx0 && vx1;                   // xx0 in [0,1022]

    const float w00 = (1.0f - wy) * (1.0f - wx);
    const float w01 = (1.0f - wy) * wx;
    const float w10 = wy * (1.0f - wx);
    const float w11 = wy * wx;

    const long r0 = (long)yy0 * IMG_W;
    const long r1 = (long)yy1 * IMG_W;

    #pragma unroll
    for (int c = 0; c < 3; ++c) {
        const float* plane = img + (size_t)c * (IMG_H * IMG_W);

        float p00 = 0.0f, p01 = 0.0f, p10 = 0.0f, p11 = 0.0f;
        if (vy0) {
            if (vpair) {
                float2 t; __builtin_memcpy(&t, plane + r0 + xx0, 8);
                p00 = t.x; p01 = t.y;
            } else if (vx0) {
                p00 = plane[r0 + xx0];
            } else if (vx1) {
                p01 = plane[r0 + xx1];
            }
        }
        if (vy1) {
            if (vpair) {
                float2 t; __builtin_memcpy(&t, plane + r1 + xx0, 8);
                p10 = t.x; p11 = t.y;
            } else if (vx0) {
                p10 = plane[r1 + xx0];
            } else if (vx1) {
                p11 = plane[r1 + xx1];
            }
        }

        const float v = p00 * w00 + p01 * w01 + p10 * w10 + p11 * w11;
        __builtin_nontemporal_store(
            v, &out[(((size_t)cut * 3 + c) * CUT_SIZE + y) * CUT_SIZE + x]);
    }
}

extern "C" void kernel_launch(void* const* d_in, const int* in_sizes, int n_in,
                              void* d_out, int out_size, void* d_ws, size_t ws_size,
                              hipStream_t stream) {
    const float* img     = (const float*)d_in[0];
    const int*   sizes_y = (const int*)d_in[1];
    const int*   sizes_x = (const int*)d_in[2];
    const int*   offs_y  = (const int*)d_in[3];
    const int*   offs_x  = (const int*)d_in[4];
    float* out = (float*)d_out;

    const int grid = CUTN * BLOCKS_PER_CUT;   // 25088 blocks of 256
    make_cutouts_kernel<<<grid, 256, 0, stream>>>(img, sizes_y, sizes_x,
                                                  offs_y, offs_x, out);
}